// Round 1
// 181.045 us; speedup vs baseline: 1.0305x; 1.0305x over previous
//
#include <hip/hip_runtime.h>
#include <hip/hip_bf16.h>
#include <stdint.h>

// Problem constants: B=2, T=2048, D=1024, H=16, HD=64
#define B_  2
#define T_  2048
#define D_  1024
#define H_  16
#define HD_ 64

typedef __bf16 bf16x8 __attribute__((ext_vector_type(8)));
typedef __bf16 bf16x4 __attribute__((ext_vector_type(4)));
typedef float  f32x4  __attribute__((ext_vector_type(4)));

__device__ __forceinline__ void async_copy16(const void* g, void* l) {
  __builtin_amdgcn_global_load_lds((__attribute__((address_space(1))) void*)(g),
                                   (__attribute__((address_space(3))) void*)(l),
                                   16, 0, 0);
}

// ---------------------------------------------------------------------------
// Fused prep (fp32 inputs hardcoded — proven R3-R9):
//   blocks [0,4096):    transpose+convert the four 1024x1024 fp32 weights to
//                       bf16, dst[n][k]=src[k][n] (wq,wk,wv->wqkv_t; wo->wo_t)
//   blocks [4096,8192): convert x fp32 -> bf16 (4 elems/thread)
// ---------------------------------------------------------------------------
__global__ void prep_kernel(const float* __restrict__ x,
                            const float* __restrict__ wq, const float* __restrict__ wk,
                            const float* __restrict__ wv, const float* __restrict__ wo,
                            __bf16* __restrict__ xc,
                            __bf16* __restrict__ wqkv_t, __bf16* __restrict__ wo_t) {
  const int id  = blockIdx.x;
  const int tid = threadIdx.x;
  if (id < 4096) {
    __shared__ __bf16 tile[32][33];
    const int z   = id >> 10;
    const int rem = id & 1023;
    const int n0 = (rem & 31) * 32, k0 = (rem >> 5) * 32;
    const int tx = tid & 31, ty = tid >> 5;
    const float* src = (z == 0) ? wq : (z == 1) ? wk : (z == 2) ? wv : wo;
    __bf16* dst = (z < 3) ? (wqkv_t + (size_t)z * 1024 * 1024) : wo_t;
#pragma unroll
    for (int i = 0; i < 4; ++i)
      tile[ty + 8 * i][tx] = (__bf16)src[(size_t)(k0 + ty + 8 * i) * 1024 + n0 + tx];
    __syncthreads();
#pragma unroll
    for (int i = 0; i < 4; ++i)
      dst[(size_t)(n0 + ty + 8 * i) * 1024 + k0 + tx] = tile[tx][ty + 8 * i];
  } else {
    const int i0 = ((id - 4096) * 256 + tid) * 4;
    bf16x4 v;
#pragma unroll
    for (int k = 0; k < 4; ++k) v[k] = (__bf16)x[i0 + k];
    *(bf16x4*)(xc + i0) = v;
  }
}

// ---------------------------------------------------------------------------
// 128x128-tile bf16 MFMA GEMM, async global_load_lds staging (validated R5).
// MODE 0: epilogue scatters Q (x0.125) / K to [b,h,t,hd], V^T to [b,h,hd,t].
// MODE 1: epilogue adds bias (fp32), stores fp32 to out.
// ---------------------------------------------------------------------------
template <int MODE>
__launch_bounds__(256)
__global__ void gemm128_kernel(const __bf16* __restrict__ A, const __bf16* __restrict__ Bt, int K,
                               __bf16* __restrict__ q_b, __bf16* __restrict__ k_b,
                               __bf16* __restrict__ vt_b,
                               const float* __restrict__ bo, float* __restrict__ outp) {
  __shared__ __align__(16) __bf16 As[128 * 64];
  __shared__ __align__(16) __bf16 Bs[128 * 64];
  const int tid  = threadIdx.x;
  const int w    = tid >> 6, lane = tid & 63;
  const int quad = lane >> 4, lr = lane & 15;
  const int tm = blockIdx.y * 128, tn = blockIdx.x * 128;
  const int wm = (w >> 1) * 64, wn = (w & 1) * 64;
  const int lrow   = lane >> 3;
  const int gchunk = (lane & 7) ^ lrow;

  f32x4 acc[4][4] = {};

  for (int k0 = 0; k0 < K; k0 += 64) {
#pragma unroll
    for (int c = 0; c < 4; ++c) {
      const int chunk = w * 4 + c;             // wave-uniform LDS base
      const int row   = chunk * 8 + lrow;
      async_copy16(A  + (size_t)(tm + row) * K + k0 + gchunk * 8, As + chunk * 512);
      async_copy16(Bt + (size_t)(tn + row) * K + k0 + gchunk * 8, Bs + chunk * 512);
    }
    __syncthreads();
#pragma unroll
    for (int ks = 0; ks < 2; ++ks) {
      bf16x8 af[4], bfr[4];
#pragma unroll
      for (int mi = 0; mi < 4; ++mi) {
        const int row = wm + mi * 16 + lr;
        const int ch  = (ks * 4 + quad) ^ (row & 7);
        af[mi] = *(const bf16x8*)(As + row * 64 + ch * 8);
      }
#pragma unroll
      for (int ni = 0; ni < 4; ++ni) {
        const int row = wn + ni * 16 + lr;
        const int ch  = (ks * 4 + quad) ^ (row & 7);
        bfr[ni] = *(const bf16x8*)(Bs + row * 64 + ch * 8);
      }
#pragma unroll
      for (int mi = 0; mi < 4; ++mi)
#pragma unroll
        for (int ni = 0; ni < 4; ++ni)
          acc[mi][ni] = __builtin_amdgcn_mfma_f32_16x16x32_bf16(af[mi], bfr[ni], acc[mi][ni], 0, 0, 0);
    }
    __syncthreads();
  }

  if (MODE == 0) {
#pragma unroll
    for (int mi = 0; mi < 4; ++mi) {
      const int mrow0 = tm + wm + mi * 16 + quad * 4;
      const int b  = mrow0 >> 11;
      const int t0 = mrow0 & 2047;
#pragma unroll
      for (int ni = 0; ni < 4; ++ni) {
        const int ncol = tn + wn + ni * 16 + lr;
        const int mat  = ncol >> 10;
        const int nn   = ncol & 1023;
        const int h = nn >> 6, hd = nn & 63;
        if (mat == 0) {
#pragma unroll
          for (int r = 0; r < 4; ++r)
            q_b[((size_t)((b * H_ + h) * T_ + t0 + r)) * HD_ + hd] =
                (__bf16)(acc[mi][ni][r] * 0.125f);
        } else if (mat == 1) {
#pragma unroll
          for (int r = 0; r < 4; ++r)
            k_b[((size_t)((b * H_ + h) * T_ + t0 + r)) * HD_ + hd] =
                (__bf16)(acc[mi][ni][r]);
        } else {
          bf16x4 pk;
#pragma unroll
          for (int r = 0; r < 4; ++r) pk[r] = (__bf16)(acc[mi][ni][r]);
          *(bf16x4*)(vt_b + ((size_t)(b * H_ + h) * HD_ + hd) * T_ + t0) = pk;
        }
      }
    }
  } else {
#pragma unroll
    for (int mi = 0; mi < 4; ++mi) {
      const int m0 = tm + wm + mi * 16 + quad * 4;
#pragma unroll
      for (int ni = 0; ni < 4; ++ni) {
        const int n = tn + wn + ni * 16 + lr;
        const float bias = bo[n];
#pragma unroll
        for (int r = 0; r < 4; ++r)
          outp[(size_t)(m0 + r) * D_ + n] = acc[mi][ni][r] + bias;
      }
    }
  }
}

// ---------------------------------------------------------------------------
// Flash attention v9 (causal). Grid 1024 linear, block 256 = 4 waves.
// Inner loop BYTE-IDENTICAL to the proven R7 structure (K/V staged per block
// into XOR-swizzled LDS, register prefetch of tile j+1, static-base softmax,
// sP dbuf pitch 72), with two changes driven by OccupancyPercent=17%:
//  1. UN-PAIRED grid: one 64-row Q tile per block, grid 512 -> 1024, so all
//     blocks are co-resident at 4 blocks/CU (LDS 34816B x4 = 139KB < 160KB),
//     doubling waves/SIMD from 2 to 4 for latency hiding.
//     Tile mapping is balanced under BOTH scheduling models:
//       - dispatch-order: round rnd=0 carries tq 24..31 (heavy first, good
//         backfill if blocks are dynamically replaced)
//       - modular residency: within-round direction alternation makes each
//         CU's 4 resident blocks sum to exactly 62+4 = 66 iterations
//         ((31-t0)+(16+t0)+(15-t0)+t0 = 62)
//     XCD head clustering preserved: bh=(id&7)*4+((id>>3)&3) -> 4 heads
//     (2 MB K/V) per XCD L2 (R8/R9-proven FETCH 122->12 MB).
//  2. s_setprio(1) around the two MFMA clusters (T5; co-resident blocks now
//     sit at diverse phases, so the CU scheduler has something to arbitrate).
// ---------------------------------------------------------------------------
__launch_bounds__(256)
__global__ void attn_kernel(const __bf16* __restrict__ q_b, const __bf16* __restrict__ k_b,
                            const __bf16* __restrict__ vt_b, __bf16* __restrict__ ctx) {
  __shared__ __align__(16) __bf16 sK[64 * 64];      // [kv][hd] XOR-swizzled
  __shared__ __align__(16) __bf16 sV[64 * 64];      // [hd][kv] XOR-swizzled
  __shared__ __align__(16) __bf16 sP[4][2][16][72]; // per-wave dbuf P tile
  const int tid  = threadIdx.x;
  const int w    = tid >> 6, lane = tid & 63;
  const int quad = lane >> 4, lr = lane & 15;
  const int id = blockIdx.x;
  const int bh  = (id & 7) * 4 + ((id >> 3) & 3);   // XCD-clustered head
  const int t0i = (id >> 5) & 7;                    // slot within round
  const int rnd = id >> 8;                          // round 0..3 (heavy first)
  const int tq  = (3 - rnd) * 8 + ((rnd & 1) ? t0i : (7 - t0i));
  const __bf16* qh = q_b  + (size_t)bh * T_ * HD_;
  const __bf16* kh = k_b  + (size_t)bh * T_ * HD_;
  const __bf16* vh = vt_b + (size_t)bh * HD_ * T_;
  const int b = bh >> 4, h = bh & 15;

  // staging geometry: 512 16B chunks per 64x64 tile; 2 chunks/thread
  const int r0 = tid >> 3, r1 = (tid + 256) >> 3;   // rows (0..63)
  const int g0 = tid & 7;                           // chunk-in-row

  const int q0 = tq * 64 + w * 16;
  const int nj = tq + 1;

  bf16x8 qf[2];
#pragma unroll
  for (int ks = 0; ks < 2; ++ks)
    qf[ks] = *(const bf16x8*)(qh + (size_t)(q0 + lr) * HD_ + ks * 32 + quad * 8);

  f32x4 o[4] = {};
  float lsum[4] = {0.f, 0.f, 0.f, 0.f};

  // prefetch tile j=0 into registers
  bf16x8 kr0 = *(const bf16x8*)(kh + (size_t)r0 * HD_ + g0 * 8);
  bf16x8 kr1 = *(const bf16x8*)(kh + (size_t)r1 * HD_ + g0 * 8);
  bf16x8 vr0 = *(const bf16x8*)(vh + (size_t)r0 * T_ + g0 * 8);
  bf16x8 vr1 = *(const bf16x8*)(vh + (size_t)r1 * T_ + g0 * 8);

  for (int j = 0; j < nj; ++j) {
    const int j0 = j * 64;
    const int pb = j & 1;
    __syncthreads();   // all waves done reading sK/sV from previous iter
    *(bf16x8*)(sK + r0 * 64 + (g0 ^ (r0 & 7)) * 8) = kr0;
    *(bf16x8*)(sK + r1 * 64 + (g0 ^ (r1 & 7)) * 8) = kr1;
    *(bf16x8*)(sV + r0 * 64 + (g0 ^ (r0 & 7)) * 8) = vr0;
    *(bf16x8*)(sV + r1 * 64 + (g0 ^ (r1 & 7)) * 8) = vr1;
    __syncthreads();
    if (j + 1 < nj) {   // overlap next-tile global loads with compute
      const int jn = j0 + 64;
      kr0 = *(const bf16x8*)(kh + (size_t)(jn + r0) * HD_ + g0 * 8);
      kr1 = *(const bf16x8*)(kh + (size_t)(jn + r1) * HD_ + g0 * 8);
      vr0 = *(const bf16x8*)(vh + (size_t)r0 * T_ + jn + g0 * 8);
      vr1 = *(const bf16x8*)(vh + (size_t)r1 * T_ + jn + g0 * 8);
    }
    // S = (Q/8) K^T for this wave's 16x64 stripe (K from LDS)
    f32x4 s[4] = {};
    __builtin_amdgcn_s_setprio(1);
#pragma unroll
    for (int ni = 0; ni < 4; ++ni) {
      const int row = ni * 16 + lr;
#pragma unroll
      for (int ks = 0; ks < 2; ++ks) {
        const int ch = (ks * 4 + quad) ^ (row & 7);
        bf16x8 kf = *(const bf16x8*)(sK + row * 64 + ch * 8);
        s[ni] = __builtin_amdgcn_mfma_f32_16x16x32_bf16(qf[ks], kf, s[ni], 0, 0, 0);
      }
    }
    __builtin_amdgcn_s_setprio(0);
    // causal mask (triggers on the last j only)
    if (j0 + 63 > q0) {
#pragma unroll
      for (int ni = 0; ni < 4; ++ni) {
        const int col = j0 + ni * 16 + lr;
#pragma unroll
        for (int r = 0; r < 4; ++r) {
          const int row = q0 + quad * 4 + r;
          if (col > row) s[ni][r] = -3.0e38f;
        }
      }
    }
    // static-base softmax: P = exp(s); per-lane partial row sums only
#pragma unroll
    for (int ni = 0; ni < 4; ++ni)
#pragma unroll
      for (int r = 0; r < 4; ++r)
        s[ni][r] = __expf(s[ni][r]);
#pragma unroll
    for (int r = 0; r < 4; ++r)
      lsum[r] += (s[0][r] + s[1][r]) + (s[2][r] + s[3][r]);
    // P (C-layout) -> LDS -> A-layout fragments (per-wave region, no barrier)
#pragma unroll
    for (int ni = 0; ni < 4; ++ni)
#pragma unroll
      for (int r = 0; r < 4; ++r)
        sP[w][pb][quad * 4 + r][ni * 16 + lr] = (__bf16)s[ni][r];
    asm volatile("s_waitcnt lgkmcnt(0)" ::: "memory");
    bf16x8 pf[2];
#pragma unroll
    for (int ks = 0; ks < 2; ++ks)
      pf[ks] = *(const bf16x8*)(&sP[w][pb][lr][ks * 32 + quad * 8]);
    // O += P * V  (V^T from LDS: row = hd, cols = kv)
    __builtin_amdgcn_s_setprio(1);
#pragma unroll
    for (int ni = 0; ni < 4; ++ni) {
      const int row = ni * 16 + lr;
#pragma unroll
      for (int ks = 0; ks < 2; ++ks) {
        const int ch = (ks * 4 + quad) ^ (row & 7);
        bf16x8 vf = *(const bf16x8*)(sV + row * 64 + ch * 8);
        o[ni] = __builtin_amdgcn_mfma_f32_16x16x32_bf16(pf[ks], vf, o[ni], 0, 0, 0);
      }
    }
    __builtin_amdgcn_s_setprio(0);
  }
  // one cross-lane reduction for the whole Q-tile (width 16 = within quad)
#pragma unroll
  for (int off = 1; off <= 8; off <<= 1)
#pragma unroll
    for (int r = 0; r < 4; ++r)
      lsum[r] += __shfl_xor(lsum[r], off, 16);
  // normalize and store ctx in merged [b*T+t][h*64+d] layout (bf16)
#pragma unroll
  for (int r = 0; r < 4; ++r) {
    const float inv = 1.0f / lsum[r];
    const int t = q0 + quad * 4 + r;
#pragma unroll
    for (int ni = 0; ni < 4; ++ni)
      ctx[((size_t)(b * T_ + t)) * D_ + h * HD_ + ni * 16 + lr] =
          (__bf16)(o[ni][r] * inv);
  }
}

// ---------------------------------------------------------------------------
extern "C" void kernel_launch(void* const* d_in, const int* in_sizes, int n_in,
                              void* d_out, int out_size, void* d_ws, size_t ws_size,
                              hipStream_t stream) {
  (void)in_sizes; (void)n_in; (void)out_size; (void)ws_size;
  const float* x  = (const float*)d_in[0];
  const float* wq = (const float*)d_in[1];
  const float* wk = (const float*)d_in[2];
  const float* wv = (const float*)d_in[3];
  const float* wo = (const float*)d_in[4];
  const float* bo = (const float*)d_in[5];
  float* outp = (float*)d_out;

  char* ws = (char*)d_ws;
  __bf16* ctx    = (__bf16*)(ws + 0);           // [4096][1024] = 8 MB
  __bf16* wqkv_t = (__bf16*)(ws + 0);           // 3072x1024 = 6 MB (dead after gemm<0>)
  __bf16* wo_t   = (__bf16*)(ws + 8388608);     // 1024x1024 = 2 MB
  __bf16* q_b    = (__bf16*)(ws + 10485760);    // [2][16][2048][64] = 8 MB
  __bf16* k_b    = (__bf16*)(ws + 18874368);    // 8 MB
  __bf16* vt_b   = (__bf16*)(ws + 27262976);    // [2][16][64][2048] = 8 MB
  __bf16* xc     = (__bf16*)(ws + 35651584);    // canonical bf16 x = 8 MB

  prep_kernel<<<8192, 256, 0, stream>>>(x, wq, wk, wv, wo, xc, wqkv_t, wo_t);
  gemm128_kernel<0><<<dim3(24, 32), 256, 0, stream>>>(xc, wqkv_t, 1024, q_b, k_b, vt_b, nullptr, nullptr);
  attn_kernel<<<1024, 256, 0, stream>>>(q_b, k_b, vt_b, ctx);
  gemm128_kernel<1><<<dim3(8, 32), 256, 0, stream>>>(ctx, wo_t, 1024, nullptr, nullptr, nullptr, bo, outp);
}

// Round 2
// 176.947 us; speedup vs baseline: 1.0544x; 1.0232x over previous
//
#include <hip/hip_runtime.h>
#include <hip/hip_bf16.h>
#include <stdint.h>

// Problem constants: B=2, T=2048, D=1024, H=16, HD=64
#define B_  2
#define T_  2048
#define D_  1024
#define H_  16
#define HD_ 64

typedef __bf16 bf16x8 __attribute__((ext_vector_type(8)));
typedef __bf16 bf16x4 __attribute__((ext_vector_type(4)));
typedef float  f32x4  __attribute__((ext_vector_type(4)));

__device__ __forceinline__ void async_copy16(const void* g, void* l) {
  __builtin_amdgcn_global_load_lds((__attribute__((address_space(1))) void*)(g),
                                   (__attribute__((address_space(3))) void*)(l),
                                   16, 0, 0);
}

// ---------------------------------------------------------------------------
// Fused prep (fp32 inputs hardcoded — proven R3-R9):
//   blocks [0,4096):    transpose+convert the four 1024x1024 fp32 weights to
//                       bf16, dst[n][k]=src[k][n] (wq,wk,wv->wqkv_t; wo->wo_t)
//   blocks [4096,8192): convert x fp32 -> bf16 (4 elems/thread)
// ---------------------------------------------------------------------------
__global__ void prep_kernel(const float* __restrict__ x,
                            const float* __restrict__ wq, const float* __restrict__ wk,
                            const float* __restrict__ wv, const float* __restrict__ wo,
                            __bf16* __restrict__ xc,
                            __bf16* __restrict__ wqkv_t, __bf16* __restrict__ wo_t) {
  const int id  = blockIdx.x;
  const int tid = threadIdx.x;
  if (id < 4096) {
    __shared__ __bf16 tile[32][33];
    const int z   = id >> 10;
    const int rem = id & 1023;
    const int n0 = (rem & 31) * 32, k0 = (rem >> 5) * 32;
    const int tx = tid & 31, ty = tid >> 5;
    const float* src = (z == 0) ? wq : (z == 1) ? wk : (z == 2) ? wv : wo;
    __bf16* dst = (z < 3) ? (wqkv_t + (size_t)z * 1024 * 1024) : wo_t;
#pragma unroll
    for (int i = 0; i < 4; ++i)
      tile[ty + 8 * i][tx] = (__bf16)src[(size_t)(k0 + ty + 8 * i) * 1024 + n0 + tx];
    __syncthreads();
#pragma unroll
    for (int i = 0; i < 4; ++i)
      dst[(size_t)(n0 + ty + 8 * i) * 1024 + k0 + tx] = tile[tx][ty + 8 * i];
  } else {
    const int i0 = ((id - 4096) * 256 + tid) * 4;
    bf16x4 v;
#pragma unroll
    for (int k = 0; k < 4; ++k) v[k] = (__bf16)x[i0 + k];
    *(bf16x4*)(xc + i0) = v;
  }
}

// ---------------------------------------------------------------------------
// 128x128-tile bf16 MFMA GEMM, async global_load_lds staging (validated R5).
// MODE 0: epilogue scatters Q (x0.125) / K to [b,h,t,hd], V^T to [b,h,hd,t].
// MODE 1: epilogue adds bias (fp32), stores fp32 to out.
// ---------------------------------------------------------------------------
template <int MODE>
__launch_bounds__(256)
__global__ void gemm128_kernel(const __bf16* __restrict__ A, const __bf16* __restrict__ Bt, int K,
                               __bf16* __restrict__ q_b, __bf16* __restrict__ k_b,
                               __bf16* __restrict__ vt_b,
                               const float* __restrict__ bo, float* __restrict__ outp) {
  __shared__ __align__(16) __bf16 As[128 * 64];
  __shared__ __align__(16) __bf16 Bs[128 * 64];
  const int tid  = threadIdx.x;
  const int w    = tid >> 6, lane = tid & 63;
  const int quad = lane >> 4, lr = lane & 15;
  const int tm = blockIdx.y * 128, tn = blockIdx.x * 128;
  const int wm = (w >> 1) * 64, wn = (w & 1) * 64;
  const int lrow   = lane >> 3;
  const int gchunk = (lane & 7) ^ lrow;

  f32x4 acc[4][4] = {};

  for (int k0 = 0; k0 < K; k0 += 64) {
#pragma unroll
    for (int c = 0; c < 4; ++c) {
      const int chunk = w * 4 + c;             // wave-uniform LDS base
      const int row   = chunk * 8 + lrow;
      async_copy16(A  + (size_t)(tm + row) * K + k0 + gchunk * 8, As + chunk * 512);
      async_copy16(Bt + (size_t)(tn + row) * K + k0 + gchunk * 8, Bs + chunk * 512);
    }
    __syncthreads();
#pragma unroll
    for (int ks = 0; ks < 2; ++ks) {
      bf16x8 af[4], bfr[4];
#pragma unroll
      for (int mi = 0; mi < 4; ++mi) {
        const int row = wm + mi * 16 + lr;
        const int ch  = (ks * 4 + quad) ^ (row & 7);
        af[mi] = *(const bf16x8*)(As + row * 64 + ch * 8);
      }
#pragma unroll
      for (int ni = 0; ni < 4; ++ni) {
        const int row = wn + ni * 16 + lr;
        const int ch  = (ks * 4 + quad) ^ (row & 7);
        bfr[ni] = *(const bf16x8*)(Bs + row * 64 + ch * 8);
      }
#pragma unroll
      for (int mi = 0; mi < 4; ++mi)
#pragma unroll
        for (int ni = 0; ni < 4; ++ni)
          acc[mi][ni] = __builtin_amdgcn_mfma_f32_16x16x32_bf16(af[mi], bfr[ni], acc[mi][ni], 0, 0, 0);
    }
    __syncthreads();
  }

  if (MODE == 0) {
#pragma unroll
    for (int mi = 0; mi < 4; ++mi) {
      const int mrow0 = tm + wm + mi * 16 + quad * 4;
      const int b  = mrow0 >> 11;
      const int t0 = mrow0 & 2047;
#pragma unroll
      for (int ni = 0; ni < 4; ++ni) {
        const int ncol = tn + wn + ni * 16 + lr;
        const int mat  = ncol >> 10;
        const int nn   = ncol & 1023;
        const int h = nn >> 6, hd = nn & 63;
        if (mat == 0) {
#pragma unroll
          for (int r = 0; r < 4; ++r)
            q_b[((size_t)((b * H_ + h) * T_ + t0 + r)) * HD_ + hd] =
                (__bf16)(acc[mi][ni][r] * 0.125f);
        } else if (mat == 1) {
#pragma unroll
          for (int r = 0; r < 4; ++r)
            k_b[((size_t)((b * H_ + h) * T_ + t0 + r)) * HD_ + hd] =
                (__bf16)(acc[mi][ni][r]);
        } else {
          bf16x4 pk;
#pragma unroll
          for (int r = 0; r < 4; ++r) pk[r] = (__bf16)(acc[mi][ni][r]);
          *(bf16x4*)(vt_b + ((size_t)(b * H_ + h) * HD_ + hd) * T_ + t0) = pk;
        }
      }
    }
  } else {
#pragma unroll
    for (int mi = 0; mi < 4; ++mi) {
      const int m0 = tm + wm + mi * 16 + quad * 4;
#pragma unroll
      for (int ni = 0; ni < 4; ++ni) {
        const int n = tn + wn + ni * 16 + lr;
        const float bias = bo[n];
#pragma unroll
        for (int r = 0; r < 4; ++r)
          outp[(size_t)(m0 + r) * D_ + n] = acc[mi][ni][r] + bias;
      }
    }
  }
}

// ---------------------------------------------------------------------------
// Flash attention v10 (causal). Grid 1024 linear, block 256 = 4 waves.
// LDS-throughput-driven restructure (R1 analysis: 88 b128/block-iter, LDS
// pipe = ~36us floor while MFMA ~5K cyc/SIMD):
//  - K-SPLIT QK^T: wave w computes S[all 64 q][keys w*16..w*16+15], reading
//    only its 2KB K slice (kf 8->2 reads/wave/iter). Q A-frags for all 4
//    q-subtiles hoisted into registers (loop-invariant, 64 VGPR).
//  - Block-shared sP[2][64][72] (same 18KB) + one extra barrier redistributes
//    P; the PV read path (pf/vf, XOR swizzle) is byte-identical to the proven
//    kernel.
//  - lsum via ones-column MFMA: ls = mfma(pf, 1s, ls) gives exact bf16-P row
//    sums in the same C-layout as o (no in-lane adds, no end shuffle-reduce,
//    denominator consistent with PV numerator).
//  - occupancy: __launch_bounds__(256,3): ~145 VGPR -> 3 blocks/CU; fine
//    because the kernel is LDS-throughput-bound, not latency-bound.
// Staging (reg prefetch, XOR swizzle), grid balance mapping (heavy-first +
// modular 66 iters/CU), XCD head clustering: unchanged from R1 (proven).
// ---------------------------------------------------------------------------
__launch_bounds__(256, 3)
__global__ void attn_kernel(const __bf16* __restrict__ q_b, const __bf16* __restrict__ k_b,
                            const __bf16* __restrict__ vt_b, __bf16* __restrict__ ctx) {
  __shared__ __align__(16) __bf16 sK[64 * 64];      // [kv][hd] XOR-swizzled
  __shared__ __align__(16) __bf16 sV[64 * 64];      // [hd][kv] XOR-swizzled
  __shared__ __align__(16) __bf16 sP[2][64][72];    // block-shared dbuf P tile
  const int tid  = threadIdx.x;
  const int w    = tid >> 6, lane = tid & 63;
  const int quad = lane >> 4, lr = lane & 15;
  const int id = blockIdx.x;
  const int bh  = (id & 7) * 4 + ((id >> 3) & 3);   // XCD-clustered head
  const int t0i = (id >> 5) & 7;                    // slot within round
  const int rnd = id >> 8;                          // round 0..3 (heavy first)
  const int tq  = (3 - rnd) * 8 + ((rnd & 1) ? t0i : (7 - t0i));
  const __bf16* qh = q_b  + (size_t)bh * T_ * HD_;
  const __bf16* kh = k_b  + (size_t)bh * T_ * HD_;
  const __bf16* vh = vt_b + (size_t)bh * HD_ * T_;
  const int b = bh >> 4, h = bh & 15;

  // staging geometry: 512 16B chunks per 64x64 tile; 2 chunks/thread
  const int r0 = tid >> 3, r1 = (tid + 256) >> 3;   // rows (0..63)
  const int g0 = tid & 7;                           // chunk-in-row

  const int q0 = tq * 64;                           // block's 64-row Q tile
  const int nj = tq + 1;
  const int w16 = w * 16;

  // Q A-frags for ALL 4 q-subtiles, hoisted (loop-invariant): 64 VGPR
  bf16x8 qf[4][2];
#pragma unroll
  for (int qs = 0; qs < 4; ++qs)
#pragma unroll
    for (int ks = 0; ks < 2; ++ks)
      qf[qs][ks] = *(const bf16x8*)(qh + (size_t)(q0 + qs * 16 + lr) * HD_ + ks * 32 + quad * 8);

  bf16x8 onesf;
#pragma unroll
  for (int j = 0; j < 8; ++j) onesf[j] = (__bf16)1.0f;

  f32x4 o[4] = {};
  f32x4 ls = {};

  // prefetch tile j=0 into registers
  bf16x8 kr0 = *(const bf16x8*)(kh + (size_t)r0 * HD_ + g0 * 8);
  bf16x8 kr1 = *(const bf16x8*)(kh + (size_t)r1 * HD_ + g0 * 8);
  bf16x8 vr0 = *(const bf16x8*)(vh + (size_t)r0 * T_ + g0 * 8);
  bf16x8 vr1 = *(const bf16x8*)(vh + (size_t)r1 * T_ + g0 * 8);

  for (int j = 0; j < nj; ++j) {
    const int j0 = j * 64;
    const int pb = j & 1;
    __syncthreads();   // all waves done reading sK/sV (and sP[pb]) from prev
    *(bf16x8*)(sK + r0 * 64 + (g0 ^ (r0 & 7)) * 8) = kr0;
    *(bf16x8*)(sK + r1 * 64 + (g0 ^ (r1 & 7)) * 8) = kr1;
    *(bf16x8*)(sV + r0 * 64 + (g0 ^ (r0 & 7)) * 8) = vr0;
    *(bf16x8*)(sV + r1 * 64 + (g0 ^ (r1 & 7)) * 8) = vr1;
    __syncthreads();
    if (j + 1 < nj) {   // overlap next-tile global loads with compute
      const int jn = j0 + 64;
      kr0 = *(const bf16x8*)(kh + (size_t)(jn + r0) * HD_ + g0 * 8);
      kr1 = *(const bf16x8*)(kh + (size_t)(jn + r1) * HD_ + g0 * 8);
      vr0 = *(const bf16x8*)(vh + (size_t)r0 * T_ + jn + g0 * 8);
      vr1 = *(const bf16x8*)(vh + (size_t)r1 * T_ + jn + g0 * 8);
    }
    // S = (Q/8) K^T, key-split: this wave's 16 keys x all 64 q rows.
    // kf slice: 2 b128 reads/wave/iter (was 8).
    const int krow = w16 + lr;
    bf16x8 kf[2];
    kf[0] = *(const bf16x8*)(sK + krow * 64 + ((quad) ^ (krow & 7)) * 8);
    kf[1] = *(const bf16x8*)(sK + krow * 64 + ((4 + quad) ^ (krow & 7)) * 8);
    f32x4 s[4] = {};
    __builtin_amdgcn_s_setprio(1);
#pragma unroll
    for (int qs = 0; qs < 4; ++qs) {
      s[qs] = __builtin_amdgcn_mfma_f32_16x16x32_bf16(qf[qs][0], kf[0], s[qs], 0, 0, 0);
      s[qs] = __builtin_amdgcn_mfma_f32_16x16x32_bf16(qf[qs][1], kf[1], s[qs], 0, 0, 0);
    }
    __builtin_amdgcn_s_setprio(0);
    // causal mask (triggers on the last j only); col fixed per lane
    if (j0 + 63 > q0) {
      const int col = j0 + w16 + lr;
#pragma unroll
      for (int qs = 0; qs < 4; ++qs)
#pragma unroll
        for (int r = 0; r < 4; ++r) {
          const int row = q0 + qs * 16 + quad * 4 + r;
          if (col > row) s[qs][r] = -3.0e38f;
        }
    }
    // static-base softmax: P = exp(s)
#pragma unroll
    for (int qs = 0; qs < 4; ++qs)
#pragma unroll
      for (int r = 0; r < 4; ++r)
        s[qs][r] = __expf(s[qs][r]);
    // scatter this wave's key-columns into block-shared sP
#pragma unroll
    for (int qs = 0; qs < 4; ++qs)
#pragma unroll
      for (int r = 0; r < 4; ++r)
        sP[pb][qs * 16 + quad * 4 + r][w16 + lr] = (__bf16)s[qs][r];
    __syncthreads();   // all waves' S columns visible
    bf16x8 pf[2];
#pragma unroll
    for (int ks = 0; ks < 2; ++ks)
      pf[ks] = *(const bf16x8*)(&sP[pb][w16 + lr][ks * 32 + quad * 8]);
    // O += P * V  (V^T from LDS: row = hd, cols = kv); row sums via ones-MFMA
    __builtin_amdgcn_s_setprio(1);
#pragma unroll
    for (int ni = 0; ni < 4; ++ni) {
      const int row = ni * 16 + lr;
#pragma unroll
      for (int ks = 0; ks < 2; ++ks) {
        const int ch = (ks * 4 + quad) ^ (row & 7);
        bf16x8 vf = *(const bf16x8*)(sV + row * 64 + ch * 8);
        o[ni] = __builtin_amdgcn_mfma_f32_16x16x32_bf16(pf[ks], vf, o[ni], 0, 0, 0);
      }
    }
    ls = __builtin_amdgcn_mfma_f32_16x16x32_bf16(pf[0], onesf, ls, 0, 0, 0);
    ls = __builtin_amdgcn_mfma_f32_16x16x32_bf16(pf[1], onesf, ls, 0, 0, 0);
    __builtin_amdgcn_s_setprio(0);
  }
  // normalize and store ctx in merged [b*T+t][h*64+d] layout (bf16).
  // ls[r] = rowsum for q = q0 + w16 + quad*4 + r (replicated over lr).
#pragma unroll
  for (int r = 0; r < 4; ++r) {
    const float inv = 1.0f / ls[r];
    const int t = q0 + w16 + quad * 4 + r;
#pragma unroll
    for (int ni = 0; ni < 4; ++ni)
      ctx[((size_t)(b * T_ + t)) * D_ + h * HD_ + ni * 16 + lr] =
          (__bf16)(o[ni][r] * inv);
  }
}

// ---------------------------------------------------------------------------
extern "C" void kernel_launch(void* const* d_in, const int* in_sizes, int n_in,
                              void* d_out, int out_size, void* d_ws, size_t ws_size,
                              hipStream_t stream) {
  (void)in_sizes; (void)n_in; (void)out_size; (void)ws_size;
  const float* x  = (const float*)d_in[0];
  const float* wq = (const float*)d_in[1];
  const float* wk = (const float*)d_in[2];
  const float* wv = (const float*)d_in[3];
  const float* wo = (const float*)d_in[4];
  const float* bo = (const float*)d_in[5];
  float* outp = (float*)d_out;

  char* ws = (char*)d_ws;
  __bf16* ctx    = (__bf16*)(ws + 0);           // [4096][1024] = 8 MB
  __bf16* wqkv_t = (__bf16*)(ws + 0);           // 3072x1024 = 6 MB (dead after gemm<0>)
  __bf16* wo_t   = (__bf16*)(ws + 8388608);     // 1024x1024 = 2 MB
  __bf16* q_b    = (__bf16*)(ws + 10485760);    // [2][16][2048][64] = 8 MB
  __bf16* k_b    = (__bf16*)(ws + 18874368);    // 8 MB
  __bf16* vt_b   = (__bf16*)(ws + 27262976);    // [2][16][64][2048] = 8 MB
  __bf16* xc     = (__bf16*)(ws + 35651584);    // canonical bf16 x = 8 MB

  prep_kernel<<<8192, 256, 0, stream>>>(x, wq, wk, wv, wo, xc, wqkv_t, wo_t);
  gemm128_kernel<0><<<dim3(24, 32), 256, 0, stream>>>(xc, wqkv_t, 1024, q_b, k_b, vt_b, nullptr, nullptr);
  attn_kernel<<<1024, 256, 0, stream>>>(q_b, k_b, vt_b, ctx);
  gemm128_kernel<1><<<dim3(8, 32), 256, 0, stream>>>(ctx, wo_t, 1024, nullptr, nullptr, nullptr, bo, outp);
}